// Round 3
// baseline (97.442 us; speedup 1.0000x reference)
//
#include <hip/hip_runtime.h>
#include <stdint.h>

#define M_DIM 4096
#define K_DIM 4096
#define N_DIM 4096

typedef int v4i __attribute__((ext_vector_type(4)));
typedef int int32x4 __attribute__((ext_vector_type(4)));

__device__ __forceinline__ void gload_lds16(const void* g, void* l) {
    __builtin_amdgcn_global_load_lds(
        (const __attribute__((address_space(1))) uint32_t*)g,
        (__attribute__((address_space(3))) uint32_t*)l, 16, 0, 0);
}

// ---------------- Pass 1: merged pack (A elementwise + B transpose) ----------------
__global__ void pack_ab_kernel(const int* __restrict__ a, char* __restrict__ a8,
                               const int* __restrict__ b, char* __restrict__ b8t) {
    __shared__ char tile[64][68];  // +4 pad (B branch only)
    if (blockIdx.x < 2048) {
        int idx = blockIdx.x * 256 + threadIdx.x;
        const int stride = 2048 * 256;
        const int total4 = M_DIM * K_DIM / 4;
        for (int i = idx; i < total4; i += stride) {
            int32x4 v = ((const int32x4*)a)[i];
            uint32_t p = (uint32_t)(v.x & 0xff) | ((uint32_t)(v.y & 0xff) << 8) |
                         ((uint32_t)(v.z & 0xff) << 16) | ((uint32_t)(v.w & 0xff) << 24);
            ((uint32_t*)a8)[i] = p;
        }
    } else {
        int bid2 = blockIdx.x - 2048;        // 0..4095
        int n0 = (bid2 & 63) * 64;
        int k0 = (bid2 >> 6) * 64;
        int tx = threadIdx.x & 63;
        int ty = threadIdx.x >> 6;  // 0..3
#pragma unroll
        for (int kk = 0; kk < 64; kk += 4) {
            tile[kk + ty][tx] = (char)b[(size_t)(k0 + kk + ty) * N_DIM + n0 + tx];
        }
        __syncthreads();
        int td = threadIdx.x & 15;  // dword index along k (0..15)
        int tn = threadIdx.x >> 4;  // 0..15
#pragma unroll
        for (int nn0 = 0; nn0 < 64; nn0 += 16) {
            int nn = nn0 + tn;
            uint32_t p = (uint32_t)(uint8_t)tile[td * 4 + 0][nn] |
                         ((uint32_t)(uint8_t)tile[td * 4 + 1][nn] << 8) |
                         ((uint32_t)(uint8_t)tile[td * 4 + 2][nn] << 16) |
                         ((uint32_t)(uint8_t)tile[td * 4 + 3][nn] << 24);
            *(uint32_t*)&b8t[(size_t)(n0 + nn) * K_DIM + k0 + td * 4] = p;
        }
    }
}

// ---------------- Pass 2: i8 GEMM, 256x256, slip-scheduled (2 barriers / K-tile) ----------------
// BM=BN=256, BK=128 i8. 8 waves (2Mx4N), 512 threads. LDS 128 KiB: 2 buf x 4 regions x 16 KiB.
//   region 0 = A kk0 (k 0..63), 1 = A kk1, 2 = B kk0, 3 = B kk1
//   chunk c of row r stored at slot c ^ ((r>>1)&3)  (conflict-free involution;
//   applied via pre-swizzled global source, linear LDS dest).
// R3 change: drop per-phase barriers. Each BK=64 half is ONE scheduling window:
//   {4 DMA stages for same half of tile t+1} {12 ds_read_b128} {32 MFMA} vmcnt(4) BAR
// Compiler interleaves reads/MFMAs with counted lgkmcnt; 2 waves/SIMD slip.
// vmcnt(4) ledger: entering kk0(t): {kk1(t)} outstanding; +4 issued -> 8;
// vm4 drains kk1(t) exactly, leaves kk0(t+1). Symmetric for kk1 halves. No
// vmcnt(0) in the loop; last tile peeled with one vmcnt(0).
#define BM 256
#define BN 256
#define BK 128
#define KTILES (K_DIM / BK)

#define BAR __builtin_amdgcn_s_barrier()
#define WAIT_VM4 asm volatile("s_waitcnt vmcnt(4)" ::: "memory")
#define WAIT_VM0 asm volatile("s_waitcnt vmcnt(0)" ::: "memory")

#define DS_A(dst, kk, ib)                                                               \
    _Pragma("unroll") for (int i_ = 0; i_ < 4; ++i_) dst[i_] =                          \
        *(const v4i*)(lds + bufOff + (kk) * 16384 + aOff + ((ib) + i_) * 1024);

#define DS_B(dst, kk)                                                                   \
    _Pragma("unroll") for (int j_ = 0; j_ < 4; ++j_) dst[j_] =                          \
        *(const v4i*)(lds + bufOff + (kk) * 16384 + bOff + j_ * 1024);

#define MM(ib, AF, BF)                                                                  \
    __builtin_amdgcn_s_setprio(1);                                                      \
    _Pragma("unroll") for (int i_ = 0; i_ < 4; ++i_)                                    \
    _Pragma("unroll") for (int j_ = 0; j_ < 4; ++j_)                                    \
        acc[(ib) + i_][j_] =                                                            \
            __builtin_amdgcn_mfma_i32_16x16x64_i8(AF[i_], BF[j_], acc[(ib) + i_][j_],   \
                                                  0, 0, 0);                             \
    __builtin_amdgcn_s_setprio(0);

__global__ __launch_bounds__(512, 2) void gemm_i8_slip(const char* __restrict__ A8,
                                                       const char* __restrict__ B8T,
                                                       const float* __restrict__ scale,
                                                       float* __restrict__ out) {
    __shared__ char lds[131072];

    int tid = threadIdx.x;
    int wave = tid >> 6;
    int lane = tid & 63;
    int wr = wave >> 2;  // 0..1 -> 128 M-rows
    int wc = wave & 3;   // 0..3 -> 64 N-cols
    int l15 = lane & 15;

    // XCD-bijective swizzle (grid = 256, 256 % 8 == 0)
    int bid = blockIdx.x;
    int swz = (bid & 7) * 32 + (bid >> 3);
    int bm = swz >> 4;  // 0..15
    int bn = swz & 15;

    // staging geometry: per-thread pre-swizzled global source; linear LDS dest
    int rA = tid >> 2;                                 // row 0..127 (+ u*128)
    int cc = ((tid & 3) ^ ((tid >> 3) & 3)) << 4;      // pre-swizzled 16B chunk in 64B row
    const char* aSrc = A8 + (size_t)(bm * BM + rA) * K_DIM + cc;
    const char* bSrc = B8T + (size_t)(bn * BN + rA) * K_DIM + cc;

    // fragment read addressing (swizzled slot; 2-way max per 16-lane group)
    int slot = (((lane >> 4) ^ ((lane >> 1) & 3)) << 4);
    int aOff = wr * 8192 + l15 * 64 + slot;            // + kk*16384 + i*1024
    int bOff = 32768 + wc * 4096 + l15 * 64 + slot;    // + kk*16384 + j*1024

    v4i acc[8][4];
#pragma unroll
    for (int i = 0; i < 8; ++i)
#pragma unroll
        for (int j = 0; j < 4; ++j) acc[i][j] = (v4i){0, 0, 0, 0};

    auto stage = [&](const char* srcBase, int kt1, int kk, int dstOff) {
        const char* s = srcBase + (size_t)kt1 * BK + kk * 64;
        char* d = (char*)lds + dstOff + wave * 1024;
        gload_lds16(s, d);
        gload_lds16(s + (size_t)128 * K_DIM, d + 8192);
    };

    // ---- prologue: stage all 4 regions of tile 0 into buf0 ----
    stage(aSrc, 0, 0, 0);              // A kk0
    stage(bSrc, 0, 0, 32768);          // B kk0
    stage(aSrc, 0, 1, 16384);          // A kk1
    stage(bSrc, 0, 1, 49152);          // B kk1
    WAIT_VM4;                          // kk0 landed; kk1 pair (4 loads) in flight
    BAR;

    int bufOff = 0;
    v4i a03[4], a47[4], b0[4];

    for (int kt = 0; kt < KTILES - 1; ++kt) {
        int nbufOff = bufOff ^ 65536;
        // ---- half kk0: stage kk0(t+1); read+MFMA kk0(t) ----
        stage(aSrc, kt + 1, 0, nbufOff + 0);
        stage(bSrc, kt + 1, 0, nbufOff + 32768);
        DS_A(a03, 0, 0);
        DS_B(b0, 0);
        DS_A(a47, 0, 4);
        MM(0, a03, b0);
        MM(4, a47, b0);
        WAIT_VM4;  // drains kk1(t); kk0(t+1) stays in flight
        BAR;
        // ---- half kk1: stage kk1(t+1); read+MFMA kk1(t) ----
        stage(aSrc, kt + 1, 1, nbufOff + 16384);
        stage(bSrc, kt + 1, 1, nbufOff + 49152);
        DS_A(a03, 1, 0);
        DS_B(b0, 1);
        DS_A(a47, 1, 4);
        MM(0, a03, b0);
        MM(4, a47, b0);
        WAIT_VM4;  // drains kk0(t+1); kk1(t+1) stays in flight
        BAR;
        bufOff = nbufOff;
    }

    // ---- final tile (no staging) ----
    DS_A(a03, 0, 0);
    DS_B(b0, 0);
    DS_A(a47, 0, 4);
    MM(0, a03, b0);
    MM(4, a47, b0);
    WAIT_VM0;  // kk1(last) landed
    BAR;
    DS_A(a03, 1, 0);
    DS_B(b0, 1);
    DS_A(a47, 1, 4);
    MM(0, a03, b0);
    MM(4, a47, b0);

    // ---- C write: out[row][col] = acc * scale[col] ----
    size_t orow0 = (size_t)bm * BM + wr * 128 + (lane >> 4) * 4;
    int ocol0 = bn * BN + wc * 64 + l15;
#pragma unroll
    for (int j = 0; j < 4; ++j) {
        int col = ocol0 + j * 16;
        float s = scale[col];
#pragma unroll
        for (int i = 0; i < 8; ++i) {
            size_t row = orow0 + (size_t)i * 16;
#pragma unroll
            for (int r = 0; r < 4; ++r) {
                out[(row + r) * N_DIM + col] = (float)acc[i][j][r] * s;
            }
        }
    }
}

// ---------------- Fallback: fused pack GEMM (no workspace needed) ----------------
#define FBM 128
#define FBN 128
#define FBK 64

__global__ __launch_bounds__(256) void gemm_i8_fused_kernel(const int* __restrict__ a,
                                                            const int* __restrict__ b,
                                                            const float* __restrict__ scale,
                                                            float* __restrict__ out) {
    __shared__ char As[FBM * FBK];
    __shared__ char Bs[FBN * FBK];

    int tid = threadIdx.x;
    int wave = tid >> 6;
    int lane = tid & 63;

    int nwg = gridDim.x;
    int cpx = nwg >> 3;
    int bid = blockIdx.x;
    int swz = (bid & 7) * cpx + (bid >> 3);
    int bm = swz >> 5;
    int bn = swz & 31;

    int f0 = tid * 16;
    int m0 = f0 >> 6;
    int k0 = f0 & 63;

    int nn = tid & 127;
    int kh = tid >> 7;  // 0..1

    int wr = wave >> 1;
    int wc = wave & 1;
    int lrow = lane & 15;
    int kgrp = (lane >> 4) * 16;

    v4i acc[4][4];
#pragma unroll
    for (int i = 0; i < 4; ++i)
#pragma unroll
        for (int j = 0; j < 4; ++j) acc[i][j] = (v4i){0, 0, 0, 0};

    const int kTiles = K_DIM / FBK;
    for (int kt = 0; kt < kTiles; ++kt) {
        __syncthreads();
#pragma unroll
        for (int r = 0; r < 2; ++r) {
            const int* src = a + (size_t)(bm * FBM + m0 + r * 64) * K_DIM + kt * FBK + k0;
            uint32_t pk[4];
#pragma unroll
            for (int q = 0; q < 4; ++q) {
                int32x4 v = *(const int32x4*)(src + q * 4);
                pk[q] = (uint32_t)(v.x & 0xff) | ((uint32_t)(v.y & 0xff) << 8) |
                        ((uint32_t)(v.z & 0xff) << 16) | ((uint32_t)(v.w & 0xff) << 24);
            }
            *(v4i*)&As[f0 + r * 4096] = (v4i){(int)pk[0], (int)pk[1], (int)pk[2], (int)pk[3]};
        }
#pragma unroll
        for (int d = 0; d < 8; ++d) {
            uint32_t p = 0;
#pragma unroll
            for (int i = 0; i < 4; ++i) {
                int kk = kt * FBK + kh * 32 + d * 4 + i;
                p |= (uint32_t)(b[(size_t)kk * N_DIM + bn * FBN + nn] & 0xff) << (8 * i);
            }
            *(uint32_t*)&Bs[nn * 64 + kh * 32 + d * 4] = p;
        }
        __syncthreads();

        v4i aF[4], bF[4];
#pragma unroll
        for (int i = 0; i < 4; ++i)
            aF[i] = *(const v4i*)&As[(wr * 64 + i * 16 + lrow) * FBK + kgrp];
#pragma unroll
        for (int j = 0; j < 4; ++j)
            bF[j] = *(const v4i*)&Bs[(wc * 64 + j * 16 + lrow) * FBK + kgrp];
#pragma unroll
        for (int i = 0; i < 4; ++i)
#pragma unroll
            for (int j = 0; j < 4; ++j)
                acc[i][j] = __builtin_amdgcn_mfma_i32_16x16x64_i8(aF[i], bF[j], acc[i][j], 0, 0, 0);
    }

    size_t orow0 = (size_t)bm * FBM + wr * 64;
    int ocol0 = bn * FBN + wc * 64;
#pragma unroll
    for (int j = 0; j < 4; ++j) {
        int col = ocol0 + j * 16 + lrow;
        float s = scale[col];
#pragma unroll
        for (int i = 0; i < 4; ++i) {
            size_t row = orow0 + i * 16 + (lane >> 4) * 4;
#pragma unroll
            for (int r = 0; r < 4; ++r) {
                out[(row + r) * N_DIM + col] = (float)acc[i][j][r] * s;
            }
        }
    }
}

extern "C" void kernel_launch(void* const* d_in, const int* in_sizes, int n_in,
                              void* d_out, int out_size, void* d_ws, size_t ws_size,
                              hipStream_t stream) {
    const int* a = (const int*)d_in[0];
    const int* b = (const int*)d_in[1];
    const float* scale = (const float*)d_in[2];
    float* out = (float*)d_out;

    size_t need = (size_t)M_DIM * K_DIM + (size_t)K_DIM * N_DIM;  // 32 MiB int8
    if (ws_size >= need) {
        char* a8 = (char*)d_ws;
        char* b8t = a8 + (size_t)M_DIM * K_DIM;
        pack_ab_kernel<<<2048 + 4096, 256, 0, stream>>>(a, a8, b, b8t);
        gemm_i8_slip<<<256, 512, 0, stream>>>(a8, b8t, scale, out);
    } else {
        gemm_i8_fused_kernel<<<1024, 256, 0, stream>>>(a, b, scale, out);
    }
}

// Round 4
// 94.294 us; speedup vs baseline: 1.0334x; 1.0334x over previous
//
#include <hip/hip_runtime.h>
#include <stdint.h>

#define M_DIM 4096
#define K_DIM 4096
#define N_DIM 4096

typedef int v4i __attribute__((ext_vector_type(4)));
typedef int int32x4 __attribute__((ext_vector_type(4)));

__device__ __forceinline__ void gload_lds16(const void* g, void* l) {
    __builtin_amdgcn_global_load_lds(
        (const __attribute__((address_space(1))) uint32_t*)g,
        (__attribute__((address_space(3))) uint32_t*)l, 16, 0, 0);
}

// ---------------- Pass 1: merged pack (A elementwise + B transpose) ----------------
__global__ void pack_ab_kernel(const int* __restrict__ a, char* __restrict__ a8,
                               const int* __restrict__ b, char* __restrict__ b8t) {
    __shared__ char tile[64][68];  // +4 pad (B branch only)
    if (blockIdx.x < 2048) {
        int idx = blockIdx.x * 256 + threadIdx.x;
        const int stride = 2048 * 256;
        const int total4 = M_DIM * K_DIM / 4;
        for (int i = idx; i < total4; i += stride) {
            int32x4 v = ((const int32x4*)a)[i];
            uint32_t p = (uint32_t)(v.x & 0xff) | ((uint32_t)(v.y & 0xff) << 8) |
                         ((uint32_t)(v.z & 0xff) << 16) | ((uint32_t)(v.w & 0xff) << 24);
            ((uint32_t*)a8)[i] = p;
        }
    } else {
        int bid2 = blockIdx.x - 2048;        // 0..4095
        int n0 = (bid2 & 63) * 64;
        int k0 = (bid2 >> 6) * 64;
        int tx = threadIdx.x & 63;
        int ty = threadIdx.x >> 6;  // 0..3
#pragma unroll
        for (int kk = 0; kk < 64; kk += 4) {
            tile[kk + ty][tx] = (char)b[(size_t)(k0 + kk + ty) * N_DIM + n0 + tx];
        }
        __syncthreads();
        int td = threadIdx.x & 15;  // dword index along k (0..15)
        int tn = threadIdx.x >> 4;  // 0..15
#pragma unroll
        for (int nn0 = 0; nn0 < 64; nn0 += 16) {
            int nn = nn0 + tn;
            uint32_t p = (uint32_t)(uint8_t)tile[td * 4 + 0][nn] |
                         ((uint32_t)(uint8_t)tile[td * 4 + 1][nn] << 8) |
                         ((uint32_t)(uint8_t)tile[td * 4 + 2][nn] << 16) |
                         ((uint32_t)(uint8_t)tile[td * 4 + 3][nn] << 24);
            *(uint32_t*)&b8t[(size_t)(n0 + nn) * K_DIM + k0 + td * 4] = p;
        }
    }
}

// ---------------- Pass 2: i8 GEMM, 256x256, deep-pipelined (vmcnt(8), 3 halves in flight) ----
// BM=BN=256, BK=128 i8. 8 waves (2Mx4N), 512 threads. LDS 128 KiB: 2 buf x 4 regions x 16 KiB.
//   region A kk0 = +0, A kk1 = +16384, B kk0 = +32768, B kk1 = +49152; buf1 = +65536
//   chunk c of row r stored at slot c ^ ((r>>1)&3)  (conflict-free involution;
//   applied via pre-swizzled global source, linear LDS dest).
// R4: deep prefetch. Windows W(t,0)/W(t,1); W(t,0) issues stage S(t+1,1),
// W(t,1) issues S(t+2,0) (into region vacated by this tile's kk0 read — barrier
// separated). Invariant: after W(t,0): outstanding=[S(t+1,0),S(t+1,1)];
// after W(t,1): [S(t+1,1),S(t+2,0)]. Every wait = vmcnt(8): drains exactly the
// half the NEXT window reads, issued ~2.5 windows earlier. Tail: 2 peeled tiles
// with vm8 -> vm4 -> vm0.
#define BM 256
#define BN 256
#define BK 128
#define KTILES (K_DIM / BK)

#define BAR __builtin_amdgcn_s_barrier()
#define WAIT_VM8 asm volatile("s_waitcnt vmcnt(8)" ::: "memory")
#define WAIT_VM4 asm volatile("s_waitcnt vmcnt(4)" ::: "memory")
#define WAIT_VM0 asm volatile("s_waitcnt vmcnt(0)" ::: "memory")

#define DS_A(dst, bo, kk, ib)                                                           \
    _Pragma("unroll") for (int i_ = 0; i_ < 4; ++i_) dst[i_] =                          \
        *(const v4i*)(lds + (bo) + (kk) * 16384 + aOff + ((ib) + i_) * 1024);

#define DS_B(dst, bo, kk)                                                               \
    _Pragma("unroll") for (int j_ = 0; j_ < 4; ++j_) dst[j_] =                          \
        *(const v4i*)(lds + (bo) + (kk) * 16384 + bOff + j_ * 1024);

#define MM(ib, AF, BF)                                                                  \
    __builtin_amdgcn_s_setprio(1);                                                      \
    _Pragma("unroll") for (int i_ = 0; i_ < 4; ++i_)                                    \
    _Pragma("unroll") for (int j_ = 0; j_ < 4; ++j_)                                    \
        acc[(ib) + i_][j_] =                                                            \
            __builtin_amdgcn_mfma_i32_16x16x64_i8(AF[i_], BF[j_], acc[(ib) + i_][j_],   \
                                                  0, 0, 0);                             \
    __builtin_amdgcn_s_setprio(0);

__global__ __launch_bounds__(512, 2) void gemm_i8_deep(const char* __restrict__ A8,
                                                       const char* __restrict__ B8T,
                                                       const float* __restrict__ scale,
                                                       float* __restrict__ out) {
    __shared__ char lds[131072];

    int tid = threadIdx.x;
    int wave = tid >> 6;
    int lane = tid & 63;
    int wr = wave >> 2;  // 0..1 -> 128 M-rows
    int wc = wave & 3;   // 0..3 -> 64 N-cols
    int l15 = lane & 15;

    // XCD-bijective swizzle (grid = 256, 256 % 8 == 0)
    int bid = blockIdx.x;
    int swz = (bid & 7) * 32 + (bid >> 3);
    int bm = swz >> 4;  // 0..15
    int bn = swz & 15;

    // staging geometry: per-thread pre-swizzled global source; linear LDS dest
    int rA = tid >> 2;                                 // row 0..127 (+ u*128)
    int cc = ((tid & 3) ^ ((tid >> 3) & 3)) << 4;      // pre-swizzled 16B chunk in 64B row
    const char* aSrc = A8 + (size_t)(bm * BM + rA) * K_DIM + cc;
    const char* bSrc = B8T + (size_t)(bn * BN + rA) * K_DIM + cc;

    // fragment read addressing (swizzled slot; 2-way max per 16-lane group)
    int slot = (((lane >> 4) ^ ((lane >> 1) & 3)) << 4);
    int aOff = wr * 8192 + l15 * 64 + slot;            // + buf + kk*16384 + i*1024
    int bOff = 32768 + wc * 4096 + l15 * 64 + slot;    // + buf + kk*16384 + j*1024

    v4i acc[8][4];
#pragma unroll
    for (int i = 0; i < 8; ++i)
#pragma unroll
        for (int j = 0; j < 4; ++j) acc[i][j] = (v4i){0, 0, 0, 0};

    auto stage = [&](const char* srcBase, int kt1, int kk, int dstOff) {
        const char* s = srcBase + (size_t)kt1 * BK + kk * 64;
        char* d = (char*)lds + dstOff + wave * 1024;
        gload_lds16(s, d);
        gload_lds16(s + (size_t)128 * K_DIM, d + 8192);
    };

    // ---- prologue: S(0,0), S(0,1), S(1,0) = 12 loads; drain S(0,0) ----
    stage(aSrc, 0, 0, 0);
    stage(bSrc, 0, 0, 32768);
    stage(aSrc, 0, 1, 16384);
    stage(bSrc, 0, 1, 49152);
    stage(aSrc, 1, 0, 65536 + 0);
    stage(bSrc, 1, 0, 65536 + 32768);
    WAIT_VM8;  // drains S(0,0); outstanding [S(0,1), S(1,0)]
    BAR;

    v4i a03[4], a47[4], b0[4];

    for (int kt = 0; kt < KTILES - 2; ++kt) {
        int curBuf = (kt & 1) << 16;
        int nxtBuf = curBuf ^ 65536;
        // ---- W(kt,0): read kk0(kt); issue S(kt+1,1) ----
        stage(aSrc, kt + 1, 1, nxtBuf + 16384);
        stage(bSrc, kt + 1, 1, nxtBuf + 49152);
        DS_A(a03, curBuf, 0, 0);
        DS_B(b0, curBuf, 0);
        DS_A(a47, curBuf, 0, 4);
        MM(0, a03, b0);
        MM(4, a47, b0);
        WAIT_VM8;  // drains S(kt,1)
        BAR;
        // ---- W(kt,1): read kk1(kt); issue S(kt+2,0) into region vacated by kk0(kt) ----
        stage(aSrc, kt + 2, 0, curBuf + 0);
        stage(bSrc, kt + 2, 0, curBuf + 32768);
        DS_A(a03, curBuf, 1, 0);
        DS_B(b0, curBuf, 1);
        DS_A(a47, curBuf, 1, 4);
        MM(0, a03, b0);
        MM(4, a47, b0);
        WAIT_VM8;  // drains S(kt+1,0)
        BAR;
    }

    // ---- tail: tiles KT-2, KT-1 ----
    {
        const int curBuf = ((KTILES - 2) & 1) << 16;
        const int nxtBuf = curBuf ^ 65536;
        // W(KT-2,0): issue S(KT-1,1)
        stage(aSrc, KTILES - 1, 1, nxtBuf + 16384);
        stage(bSrc, KTILES - 1, 1, nxtBuf + 49152);
        DS_A(a03, curBuf, 0, 0);
        DS_B(b0, curBuf, 0);
        DS_A(a47, curBuf, 0, 4);
        MM(0, a03, b0);
        MM(4, a47, b0);
        WAIT_VM8;  // drains S(KT-2,1)
        BAR;
        // W(KT-2,1): no issue
        DS_A(a03, curBuf, 1, 0);
        DS_B(b0, curBuf, 1);
        DS_A(a47, curBuf, 1, 4);
        MM(0, a03, b0);
        MM(4, a47, b0);
        WAIT_VM4;  // drains S(KT-1,0)
        BAR;
        // W(KT-1,0)
        DS_A(a03, nxtBuf, 0, 0);
        DS_B(b0, nxtBuf, 0);
        DS_A(a47, nxtBuf, 0, 4);
        MM(0, a03, b0);
        MM(4, a47, b0);
        WAIT_VM0;  // drains S(KT-1,1)
        BAR;
        // W(KT-1,1)
        DS_A(a03, nxtBuf, 1, 0);
        DS_B(b0, nxtBuf, 1);
        DS_A(a47, nxtBuf, 1, 4);
        MM(0, a03, b0);
        MM(4, a47, b0);
    }

    // ---- C write: out[row][col] = acc * scale[col] ----
    size_t orow0 = (size_t)bm * BM + wr * 128 + (lane >> 4) * 4;
    int ocol0 = bn * BN + wc * 64 + l15;
#pragma unroll
    for (int j = 0; j < 4; ++j) {
        int col = ocol0 + j * 16;
        float s = scale[col];
#pragma unroll
        for (int i = 0; i < 8; ++i) {
            size_t row = orow0 + (size_t)i * 16;
#pragma unroll
            for (int r = 0; r < 4; ++r) {
                out[(row + r) * N_DIM + col] = (float)acc[i][j][r] * s;
            }
        }
    }
}

// ---------------- Fallback: fused pack GEMM (no workspace needed) ----------------
#define FBM 128
#define FBN 128
#define FBK 64

__global__ __launch_bounds__(256) void gemm_i8_fused_kernel(const int* __restrict__ a,
                                                            const int* __restrict__ b,
                                                            const float* __restrict__ scale,
                                                            float* __restrict__ out) {
    __shared__ char As[FBM * FBK];
    __shared__ char Bs[FBN * FBK];

    int tid = threadIdx.x;
    int wave = tid >> 6;
    int lane = tid & 63;

    int nwg = gridDim.x;
    int cpx = nwg >> 3;
    int bid = blockIdx.x;
    int swz = (bid & 7) * cpx + (bid >> 3);
    int bm = swz >> 5;
    int bn = swz & 31;

    int f0 = tid * 16;
    int m0 = f0 >> 6;
    int k0 = f0 & 63;

    int nn = tid & 127;
    int kh = tid >> 7;  // 0..1

    int wr = wave >> 1;
    int wc = wave & 1;
    int lrow = lane & 15;
    int kgrp = (lane >> 4) * 16;

    v4i acc[4][4];
#pragma unroll
    for (int i = 0; i < 4; ++i)
#pragma unroll
        for (int j = 0; j < 4; ++j) acc[i][j] = (v4i){0, 0, 0, 0};

    const int kTiles = K_DIM / FBK;
    for (int kt = 0; kt < kTiles; ++kt) {
        __syncthreads();
#pragma unroll
        for (int r = 0; r < 2; ++r) {
            const int* src = a + (size_t)(bm * FBM + m0 + r * 64) * K_DIM + kt * FBK + k0;
            uint32_t pk[4];
#pragma unroll
            for (int q = 0; q < 4; ++q) {
                int32x4 v = *(const int32x4*)(src + q * 4);
                pk[q] = (uint32_t)(v.x & 0xff) | ((uint32_t)(v.y & 0xff) << 8) |
                        ((uint32_t)(v.z & 0xff) << 16) | ((uint32_t)(v.w & 0xff) << 24);
            }
            *(v4i*)&As[f0 + r * 4096] = (v4i){(int)pk[0], (int)pk[1], (int)pk[2], (int)pk[3]};
        }
#pragma unroll
        for (int d = 0; d < 8; ++d) {
            uint32_t p = 0;
#pragma unroll
            for (int i = 0; i < 4; ++i) {
                int kk = kt * FBK + kh * 32 + d * 4 + i;
                p |= (uint32_t)(b[(size_t)kk * N_DIM + bn * FBN + nn] & 0xff) << (8 * i);
            }
            *(uint32_t*)&Bs[nn * 64 + kh * 32 + d * 4] = p;
        }
        __syncthreads();

        v4i aF[4], bF[4];
#pragma unroll
        for (int i = 0; i < 4; ++i)
            aF[i] = *(const v4i*)&As[(wr * 64 + i * 16 + lrow) * FBK + kgrp];
#pragma unroll
        for (int j = 0; j < 4; ++j)
            bF[j] = *(const v4i*)&Bs[(wc * 64 + j * 16 + lrow) * FBK + kgrp];
#pragma unroll
        for (int i = 0; i < 4; ++i)
#pragma unroll
            for (int j = 0; j < 4; ++j)
                acc[i][j] = __builtin_amdgcn_mfma_i32_16x16x64_i8(aF[i], bF[j], acc[i][j], 0, 0, 0);
    }

    size_t orow0 = (size_t)bm * FBM + wr * 64;
    int ocol0 = bn * FBN + wc * 64;
#pragma unroll
    for (int j = 0; j < 4; ++j) {
        int col = ocol0 + j * 16 + lrow;
        float s = scale[col];
#pragma unroll
        for (int i = 0; i < 4; ++i) {
            size_t row = orow0 + i * 16 + (lane >> 4) * 4;
#pragma unroll
            for (int r = 0; r < 4; ++r) {
                out[(row + r) * N_DIM + col] = (float)acc[i][j][r] * s;
            }
        }
    }
}

extern "C" void kernel_launch(void* const* d_in, const int* in_sizes, int n_in,
                              void* d_out, int out_size, void* d_ws, size_t ws_size,
                              hipStream_t stream) {
    const int* a = (const int*)d_in[0];
    const int* b = (const int*)d_in[1];
    const float* scale = (const float*)d_in[2];
    float* out = (float*)d_out;

    size_t need = (size_t)M_DIM * K_DIM + (size_t)K_DIM * N_DIM;  // 32 MiB int8
    if (ws_size >= need) {
        char* a8 = (char*)d_ws;
        char* b8t = a8 + (size_t)M_DIM * K_DIM;
        pack_ab_kernel<<<2048 + 4096, 256, 0, stream>>>(a, a8, b, b8t);
        gemm_i8_deep<<<256, 512, 0, stream>>>(a8, b8t, scale, out);
    } else {
        gemm_i8_fused_kernel<<<1024, 256, 0, stream>>>(a, b, scale, out);
    }
}